// Round 13
// baseline (418.403 us; speedup 1.0000x reference)
//
#include <hip/hip_runtime.h>
#include <hip/hip_bf16.h>
#include <cstdint>

#define USER_NUM 30000
#define ITEM_NUM 70000
#define NTOT     100000   // USER_NUM + ITEM_NUM

typedef __attribute__((ext_vector_type(8))) short bf16x8;
typedef __attribute__((ext_vector_type(8))) ushort u16x8;
typedef __attribute__((ext_vector_type(4))) float f32x4;
typedef __attribute__((ext_vector_type(4))) unsigned int u32x4;

// async global->LDS DMA, 16B per lane (dest = wave-uniform base + lane*16)
typedef __attribute__((address_space(1))) const unsigned int gu32;
typedef __attribute__((address_space(3))) unsigned int lu32;
__device__ __forceinline__ void dma16(const void* g, void* l) {
    __builtin_amdgcn_global_load_lds((gu32*)g, (lu32*)l, 16, 0, 0);
}

// fp32 -> (hi, lo) bf16 pair via truncation; a ~= hi + lo to ~2^-16 rel.
__device__ __forceinline__ void split2(float x, ushort& h, ushort& l) {
    unsigned u = __builtin_bit_cast(unsigned int, x);
    h = (ushort)(u >> 16);
    float hf = __builtin_bit_cast(float, u & 0xffff0000u);
    float lo = x - hf;
    l = (ushort)(__builtin_bit_cast(unsigned int, lo) >> 16);
}

// pack hi16(x0) into low half, hi16(x1) into high half (one v_perm_b32)
__device__ __forceinline__ unsigned int pk_hi(unsigned int x0, unsigned int x1) {
    return __builtin_amdgcn_perm(x1, x0, 0x07060302u);
}

// convert 8 fp32 -> bf16 hi/lo of value and of square (v_perm-packed pairs)
__device__ __forceinline__ void cvt8(const float4& a, const float4& b,
                                     bf16x8& vh, bf16x8& vl, bf16x8& sh, bf16x8& sl) {
    const float f[8] = {a.x, a.y, a.z, a.w, b.x, b.y, b.z, b.w};
    unsigned int ph[4], pl[4], qh[4], ql[4];
#pragma unroll
    for (int p = 0; p < 4; ++p) {
        float f0 = f[2 * p], f1 = f[2 * p + 1];
        unsigned int u0 = __builtin_bit_cast(unsigned int, f0);
        unsigned int u1 = __builtin_bit_cast(unsigned int, f1);
        ph[p] = pk_hi(u0, u1);
        float hf0 = __builtin_bit_cast(float, u0 & 0xffff0000u);
        float hf1 = __builtin_bit_cast(float, u1 & 0xffff0000u);
        pl[p] = pk_hi(__builtin_bit_cast(unsigned int, f0 - hf0),
                      __builtin_bit_cast(unsigned int, f1 - hf1));
        float s0 = f0 * f0, s1 = f1 * f1;
        unsigned int v0 = __builtin_bit_cast(unsigned int, s0);
        unsigned int v1 = __builtin_bit_cast(unsigned int, s1);
        qh[p] = pk_hi(v0, v1);
        float sh0 = __builtin_bit_cast(float, v0 & 0xffff0000u);
        float sh1 = __builtin_bit_cast(float, v1 & 0xffff0000u);
        ql[p] = pk_hi(__builtin_bit_cast(unsigned int, s0 - sh0),
                      __builtin_bit_cast(unsigned int, s1 - sh1));
    }
    vh = __builtin_bit_cast(bf16x8, u32x4{ph[0], ph[1], ph[2], ph[3]});
    vl = __builtin_bit_cast(bf16x8, u32x4{pl[0], pl[1], pl[2], pl[3]});
    sh = __builtin_bit_cast(bf16x8, u32x4{qh[0], qh[1], qh[2], qh[3]});
    sl = __builtin_bit_cast(bf16x8, u32x4{ql[0], ql[1], ql[2], ql[3]});
}

// ---------------------------------------------------------------------------
// v15: CSR chain fused into ONE plain-launch kernel with a software grid
// barrier. (v12's hipLaunchCooperativeKernel crashed under graph capture —
// the LAUNCH API was the problem; the fusion itself is safe because all 98
// blocks (16 waves each) are co-resident on 256 CUs.) Device-scope atomics
// + __threadfence per G16 for cross-XCD coherence. The barrier counter is
// zeroed by init_and_split, which runs every graph execution.
// ---------------------------------------------------------------------------

// zero counts+fill+bar AND split all 5 weight matrices (independent, 1 launch)
__global__ void init_and_split(int* __restrict__ counts, int n2, int* __restrict__ bar,
                               const float* __restrict__ W10, const float* __restrict__ W20,
                               const float* __restrict__ W11, const float* __restrict__ W21,
                               const float* __restrict__ T1,
                               ushort* __restrict__ W10h, ushort* __restrict__ W10l,
                               ushort* __restrict__ W20h, ushort* __restrict__ W20l,
                               ushort* __restrict__ W11h, ushort* __restrict__ W11l,
                               ushort* __restrict__ W21h, ushort* __restrict__ W21l,
                               ushort* __restrict__ T1h,  ushort* __restrict__ T1l) {
    int i = blockIdx.x * blockDim.x + threadIdx.x;
    if (i == 0) *bar = 0;
    if (i < n2) counts[i] = 0;
    int j = i;
    if (j < 139264) {
        const float* src; ushort *dh, *dl;
        if (j < 32768)                   { src = W10; dh = W10h; dl = W10l; }
        else if ((j -= 32768) < 32768)   { src = W20; dh = W20h; dl = W20l; }
        else if ((j -= 32768) < 8192)    { src = W11; dh = W11h; dl = W11l; }
        else if ((j -= 8192) < 8192)     { src = W21; dh = W21h; dl = W21l; }
        else                             { j -= 8192; src = T1; dh = T1h; dl = T1l; }
        ushort h, l;
        split2(src[j], h, l);
        dh[j] = h;
        dl[j] = l;
    }
}

// software grid barrier: requires ALL blocks co-resident (98 blocks of 16
// waves on 256 CUs -> guaranteed). Device-scope atomics; monotone counter.
__device__ __forceinline__ void grid_barrier(int* bar, int target) {
    __syncthreads();
    if (threadIdx.x == 0) {
        __threadfence();                       // release all prior writes
        atomicAdd(bar, 1);                     // device-scope by default
        while (atomicAdd(bar, 0) < target)     // atomic load, stays coherent
            __builtin_amdgcn_s_sleep(1);
        __threadfence();                       // acquire
    }
    __syncthreads();
}

__global__ __launch_bounds__(1024)
void build_csr_spin(const int* __restrict__ erow, const int* __restrict__ ecol,
                    const float* __restrict__ eval,
                    int* __restrict__ counts,  // counts[n] followed by fill[n]
                    int* __restrict__ row_ptr, int* __restrict__ blk_sums,
                    int* __restrict__ scol, float* __restrict__ sval,
                    int n, int nnz, int* __restrict__ bar) {
    const int nb  = gridDim.x;
    const int tid = blockIdx.x * 1024 + threadIdx.x;
    const int nt  = nb * 1024;
    __shared__ int sd[1024];

    // ---- phase 0: histogram ----
    for (int i = tid; i < nnz; i += nt) atomicAdd(&counts[erow[i]], 1);
    grid_barrier(bar, nb);

    // ---- phase 1: block-local exclusive scan -> row_ptr; totals -> blk_sums ----
    {
        int v = (tid < n) ? counts[tid] : 0;
        sd[threadIdx.x] = v;
        __syncthreads();
        for (int off = 1; off < 1024; off <<= 1) {
            int t2 = (threadIdx.x >= (unsigned)off) ? sd[threadIdx.x - off] : 0;
            __syncthreads();
            sd[threadIdx.x] += t2;
            __syncthreads();
        }
        if (tid < n) row_ptr[tid] = sd[threadIdx.x] - v;
        if (threadIdx.x == 1023) blk_sums[blockIdx.x] = sd[1023];
    }
    grid_barrier(bar, 2 * nb);

    // ---- phase 2: every block redundantly scans blk_sums; add exclusive prefix ----
    {
        if (threadIdx.x < 128)
            sd[threadIdx.x] = ((int)threadIdx.x < nb) ? blk_sums[threadIdx.x] : 0;
        __syncthreads();
        for (int off = 1; off < 128; off <<= 1) {
            int t2 = (threadIdx.x < 128 && threadIdx.x >= (unsigned)off) ? sd[threadIdx.x - off] : 0;
            __syncthreads();
            if (threadIdx.x < 128) sd[threadIdx.x] += t2;
            __syncthreads();
        }
        int add = (blockIdx.x == 0) ? 0 : sd[blockIdx.x - 1];
        if (tid < n) row_ptr[tid] += add;
        if (tid == 0) row_ptr[n] = nnz;
    }
    grid_barrier(bar, 3 * nb);

    // ---- phase 3: scatter edges into CSR ----
    int* fill = counts + n;
    for (int i = tid; i < nnz; i += nt) {
        int r = erow[i];
        int pos = row_ptr[r] + atomicAdd(&fill[r], 1);
        scol[pos] = ecol[i];
        sval[pos] = eval[i];
    }
}

// ---------------------------------------------------------------------------
// Dual split-bf16 MFMA GEMM, v8 structure (DMA staging + LDS double-buffer):
//   C1 = A @ W1^T + b1 + b2 ;  C2 = (A @ W1^T) + (A*A) @ W2^T
// TM=128, block 256 = 4 waves, wave tile 32 rows x TN (row-exclusive). BK=32.
// PLATEAU (v7-v10): all staging structures land 91-102us; no pipe >28% busy.
// Frozen.
// ---------------------------------------------------------------------------

template <int TN, int KK>
__global__ __launch_bounds__(256, 2)
void gemm_dual_mfma(const float* __restrict__ xa, const float* __restrict__ xb, int split,
                    const ushort* __restrict__ W1h, const ushort* __restrict__ W1l,
                    const ushort* __restrict__ W2h, const ushort* __restrict__ W2l,
                    const float* __restrict__ bias1, const float* __restrict__ bias2,
                    float* __restrict__ C1, float* __restrict__ C2,
                    int M, int Nout) {
    constexpr int TM = 128, BK = 32;
    constexpr int NITER = KK / BK;
    constexpr int NI = TN / 16;             // 4
    constexpr int MI = 2;                   // 32 rows per wave
    static_assert(NITER % 2 == 0, "double-buffer unroll needs even NITER");
    __shared__ float Araw0[TM * BK], Araw1[TM * BK];      // 2 x 16KB, linear [128][32]
    __shared__ ushort Wt0[4][TN * BK], Wt1[4][TN * BK];   // 2 x 16KB, linear [64][32]

    const int m0 = blockIdx.y * TM;
    const int n0 = blockIdx.x * TN;
    const int t  = threadIdx.x;
    const int lane = t & 63, w = t >> 6;
    const int lm = lane & 15, lq = lane >> 4;

    // ---- A staging map: 4 DMA calls/wave ----
    const float* asrc[4];
#pragma unroll
    for (int c = 0; c < 4; ++c) {
        int loff = w * 4096 + c * 1024 + lane * 16;   // byte offset in A buffer
        int row  = loff >> 7;                          // 128 B rows
        int slot = (loff >> 4) & 7;
        int gm = m0 + row;
        const float* rp = xa;
        if (gm < M) rp = (gm < split) ? xa + (size_t)gm * KK
                                      : xb + (size_t)(gm - split) * KK;
        asrc[c] = rp + (slot ^ (row & 7)) * 4;         // pre-swizzled source
    }
    // ---- W staging map: 1 DMA call/wave/array ----
    const ushort* wsrc[4] = {W1h, W1l, W2h, W2l};
    const ushort* wptr[4];
#pragma unroll
    for (int p = 0; p < 4; ++p) {
        int loff = w * 1024 + lane * 16;               // byte offset in array
        int row  = loff >> 6;                          // 64 B rows
        int slot = (loff >> 4) & 3;
        wptr[p] = wsrc[p] + (size_t)(n0 + row) * KK + (slot ^ (row & 3)) * 8;
    }

    // read-side swizzled offsets (elements); row&7 == lm&7, row&3 == lm&3
    const int sA0 = ((lq * 2 + 0) ^ (lm & 7)) * 4;
    const int sA1 = ((lq * 2 + 1) ^ (lm & 7)) * 4;
    const int sW  = (lq ^ (lm & 3)) * 8;

    f32x4 acc1[MI][NI] = {};
    f32x4 acc2[MI][NI] = {};

    auto stage = [&](float* Ad, ushort (*Wd)[TN * BK], int k0) {
#pragma unroll
        for (int c = 0; c < 4; ++c)
            dma16(asrc[c] + k0, (char*)Ad + w * 4096 + c * 1024);
#pragma unroll
        for (int p = 0; p < 4; ++p)
            dma16(wptr[p] + k0, (char*)Wd + p * 4096 + w * 1024);
    };

    auto compute = [&](const float* Ar, const ushort (*Wr)[TN * BK]) {
#pragma unroll
        for (int mi = 0; mi < MI; ++mi) {
            const int row = w * 32 + mi * 16 + lm;
            const float* ap = Ar + row * 32;
            float4 x0 = *(const float4*)(ap + sA0);
            float4 x1 = *(const float4*)(ap + sA1);
            bf16x8 vah, val, vqh, vql;
            cvt8(x0, x1, vah, val, vqh, vql);
#pragma unroll
            for (int ni = 0; ni < NI; ++ni) {
                const int woff = (ni * 16 + lm) * 32 + sW;
                bf16x8 b1h = *(const bf16x8*)(Wr[0] + woff);
                bf16x8 b1l = *(const bf16x8*)(Wr[1] + woff);
                bf16x8 b2h = *(const bf16x8*)(Wr[2] + woff);
                bf16x8 b2l = *(const bf16x8*)(Wr[3] + woff);
                acc1[mi][ni] = __builtin_amdgcn_mfma_f32_16x16x32_bf16(vah, b1h, acc1[mi][ni], 0, 0, 0);
                acc1[mi][ni] = __builtin_amdgcn_mfma_f32_16x16x32_bf16(vah, b1l, acc1[mi][ni], 0, 0, 0);
                acc1[mi][ni] = __builtin_amdgcn_mfma_f32_16x16x32_bf16(val, b1h, acc1[mi][ni], 0, 0, 0);
                acc2[mi][ni] = __builtin_amdgcn_mfma_f32_16x16x32_bf16(vqh, b2h, acc2[mi][ni], 0, 0, 0);
                acc2[mi][ni] = __builtin_amdgcn_mfma_f32_16x16x32_bf16(vqh, b2l, acc2[mi][ni], 0, 0, 0);
                acc2[mi][ni] = __builtin_amdgcn_mfma_f32_16x16x32_bf16(vql, b2h, acc2[mi][ni], 0, 0, 0);
            }
        }
    };

    // prologue: tile 0 latency exposed once
    stage(Araw0, Wt0, 0);
    __syncthreads();

    for (int it = 0; it < NITER; it += 2) {
        stage(Araw1, Wt1, (it + 1) * BK);     // in flight during compute
        compute(Araw0, Wt0);
        __syncthreads();
        if (it + 2 < NITER) stage(Araw0, Wt0, (it + 2) * BK);
        compute(Araw1, Wt1);
        __syncthreads();
    }

    // ---- epilogue: C/D layout col=lane&15, row=lq*4+r; biases folded into C1 ----
#pragma unroll
    for (int mi = 0; mi < MI; ++mi)
#pragma unroll
        for (int ni = 0; ni < NI; ++ni)
#pragma unroll
            for (int r = 0; r < 4; ++r) {
                int gm = m0 + w * 32 + mi * 16 + lq * 4 + r;
                int gn = n0 + ni * 16 + lm;
                if (gm < M && gn < Nout) {
                    size_t o = (size_t)gm * Nout + gn;
                    float g1 = acc1[mi][ni][r];
                    C1[o] = g1 + bias1[gn] + bias2[gn];
                    C2[o] = g1 + acc2[mi][ni][r];
                }
            }
}

// ---------------------------------------------------------------------------
// T1 GEMM with fused gather + FUSED T2/T3 TAIL (v11, kept):
//   e1 = relu( [final[u] ; final[it+U]] @ T1_W^T + T1_b )   (64 cols, in LDS)
//   out[b] = T3_W . relu(T2_W @ e1[b] + T2_b) + T3_b
// TM=64, grid (1,256): full GPU. e1 never touches global.
// ---------------------------------------------------------------------------

template <int TN, int KK>
__global__ __launch_bounds__(256, 4)
void gemm_t1_mfma(const int* __restrict__ userIdx, const int* __restrict__ itemIdx,
                  const float* __restrict__ uEmbd, const float* __restrict__ iEmbd,
                  const float* __restrict__ f1, const float* __restrict__ f2,
                  const ushort* __restrict__ Wh, const ushort* __restrict__ Wl,
                  const float* __restrict__ bias,
                  const float* __restrict__ T2_W, const float* __restrict__ T2_b,
                  const float* __restrict__ T3_W, const float* __restrict__ T3_b,
                  float* __restrict__ out, int M) {
    constexpr int TM = 64, BK = 32, SR = 40;
    constexpr int NITER = KK / BK;            // 28
    constexpr int WTM = 32, WTN = TN / 2;     // 32 x 32 wave tiles
    constexpr int MI = WTM / 16, NI = WTN / 16;
    __shared__ ushort Ah[TM * SR], Al[TM * SR];   // 2 x 5120 B
    __shared__ float e1t[64][68];                 // 17408 B; total 27.6KB -> 4 blk/CU

    const int m0 = blockIdx.y * TM;
    const int n0 = blockIdx.x * TN;               // always 0 (grid.x = 1)
    const int t  = threadIdx.x;
    const int lane = t & 63, w = t >> 6;
    const int wm = w & 1, wn = w >> 1;
    const int lm = lane & 15, lq = lane >> 4;

    const int srow = t >> 2, spart = t & 3;   // 4 threads per row, 8 floats each
    const int b = m0 + srow;
    const bool svalid = (b < M);
    int unode = 0, gnode = 0;
    if (svalid) { unode = userIdx[b]; gnode = itemIdx[b] + USER_NUM; }
    const int sbase = srow * SR + spart * 8;

    auto gload = [&](int it, float4* v) {
        v[0] = float4{0.f, 0.f, 0.f, 0.f};
        v[1] = float4{0.f, 0.f, 0.f, 0.f};
        if (!svalid) return;
        int c0 = it * BK + spart * 8;
        int node = (c0 < 448) ? unode : gnode;
        int cc = (c0 < 448) ? c0 : c0 - 448;
        const float* p;
        if (cc < 256)
            p = (node < USER_NUM) ? uEmbd + (size_t)node * 256 + cc
                                  : iEmbd + (size_t)(node - USER_NUM) * 256 + cc;
        else if (cc < 384) p = f1 + (size_t)node * 128 + (cc - 256);
        else               p = f2 + (size_t)node * 64  + (cc - 384);
        v[0] = *(const float4*)p;
        v[1] = *(const float4*)(p + 4);
    };

    f32x4 acc[MI][NI] = {};

    float4 cur[2];
    gload(0, cur);

    for (int it = 0; it < NITER; ++it) {
        // ---- write current tile (hi/lo split) to LDS ----
        {
            ushort hb[8], lb[8];
            const float av[8] = {cur[0].x, cur[0].y, cur[0].z, cur[0].w,
                                 cur[1].x, cur[1].y, cur[1].z, cur[1].w};
#pragma unroll
            for (int j = 0; j < 8; ++j) split2(av[j], hb[j], lb[j]);
            *(u16x8*)(Ah + sbase) = *(const u16x8*)&hb[0];
            *(u16x8*)(Al + sbase) = *(const u16x8*)&lb[0];
        }
        __syncthreads();

        // ---- T14 issue-early: next tile's gather loads fly during compute ----
        float4 nxt[2];
        if (it + 1 < NITER) gload(it + 1, nxt);

        const int k0 = it * BK;
        bf16x8 bh[NI], bl[NI];
#pragma unroll
        for (int ni = 0; ni < NI; ++ni) {
            size_t wo = (size_t)(n0 + wn * WTN + ni * 16 + lm) * KK + k0 + lq * 8;
            bh[ni] = *(const bf16x8*)(Wh + wo);
            bl[ni] = *(const bf16x8*)(Wl + wo);
        }
#pragma unroll
        for (int mi = 0; mi < MI; ++mi) {
            int off = (wm * WTM + mi * 16 + lm) * SR + lq * 8;
            bf16x8 ah = *(const bf16x8*)(Ah + off);
            bf16x8 al = *(const bf16x8*)(Al + off);
#pragma unroll
            for (int ni = 0; ni < NI; ++ni) {
                acc[mi][ni] = __builtin_amdgcn_mfma_f32_16x16x32_bf16(ah, bh[ni], acc[mi][ni], 0, 0, 0);
                acc[mi][ni] = __builtin_amdgcn_mfma_f32_16x16x32_bf16(ah, bl[ni], acc[mi][ni], 0, 0, 0);
                acc[mi][ni] = __builtin_amdgcn_mfma_f32_16x16x32_bf16(al, bh[ni], acc[mi][ni], 0, 0, 0);
            }
        }
        __syncthreads();
        cur[0] = nxt[0];
        cur[1] = nxt[1];
    }

    // ---- e1 tile -> LDS (relu + bias), then fused T2+T3 tail ----
#pragma unroll
    for (int mi = 0; mi < MI; ++mi)
#pragma unroll
        for (int ni = 0; ni < NI; ++ni)
#pragma unroll
            for (int r = 0; r < 4; ++r) {
                int lr = wm * WTM + mi * 16 + lq * 4 + r;   // 0..63
                int lc = wn * WTN + ni * 16 + lm;           // 0..63
                e1t[lr][lc] = fmaxf(acc[mi][ni][r] + bias[lc], 0.f);
            }
    __syncthreads();

    {
        const int row = t >> 2;          // 0..63: local e1 row
        const int gb  = m0 + row;
        float s = 0.f;
        if (gb < M) {
#pragma unroll
            for (int jj = 0; jj < 8; ++jj) {
                int j = (t & 3) * 8 + jj;            // 0..31: T2 row
                const float* wr = T2_W + j * 64;
                float d = T2_b[j];
#pragma unroll
                for (int k = 0; k < 64; ++k) d += e1t[row][k] * wr[k];
                s += fmaxf(d, 0.f) * T3_W[j];
            }
        }
        s += __shfl_down(s, 2, 4);
        s += __shfl_down(s, 1, 4);
        if ((t & 3) == 0 && gb < M) out[gb] = s + T3_b[0];
    }
}

// ---------------------------------------------------------------------------
// Fused SPMM epilogue (biases pre-folded into G1):
//   out[r,:] = sum_e val_e * H[col_e,:] + G1[r,:]
// Layer 0 uses the dense-row form (all N rows needed by the L1 GEMM).
// ---------------------------------------------------------------------------

template <int VEC>
__global__ __launch_bounds__(256)
void spmm_fused(const int* __restrict__ row_ptr, const int* __restrict__ scol,
                const float* __restrict__ sval, const float* __restrict__ H,
                const float* __restrict__ G1, float* __restrict__ out, int n) {
    constexpr int W = 64 * VEC;
    int r = blockIdx.x * 4 + (threadIdx.x >> 6);
    if (r >= n) return;
    int base = (threadIdx.x & 63) * VEC;
    float acc[VEC];
    const float* g = G1 + (size_t)r * W + base;
#pragma unroll
    for (int v = 0; v < VEC; ++v) acc[v] = g[v];
    int e0 = row_ptr[r], e1 = row_ptr[r + 1];
    int e = e0;
    for (; e + 1 < e1; e += 2) {
        int c0 = scol[e], c1 = scol[e + 1];
        float v0 = sval[e], v1 = sval[e + 1];
        const float* h0 = H + (size_t)c0 * W + base;
        const float* h1 = H + (size_t)c1 * W + base;
#pragma unroll
        for (int v = 0; v < VEC; ++v) acc[v] += v0 * h0[v] + v1 * h1[v];
    }
    if (e < e1) {
        int c = scol[e];
        float val = sval[e];
        const float* h = H + (size_t)c * W + base;
#pragma unroll
        for (int v = 0; v < VEC; ++v) acc[v] += val * h[v];
    }
    float* o = out + (size_t)r * W + base;
#pragma unroll
    for (int v = 0; v < VEC; ++v) o[v] = acc[v];
}

// ---------------------------------------------------------------------------
// List-driven SPMM for layer 1 (v14): f2 is consumed ONLY by the t1 gather at
// rows {userIdx} ∪ {itemIdx+USER_NUM}; compute just those 2B row-instances.
// ---------------------------------------------------------------------------

__global__ __launch_bounds__(256)
void spmm_fused_list(const int* __restrict__ userIdx, const int* __restrict__ itemIdx,
                     int B,
                     const int* __restrict__ row_ptr, const int* __restrict__ scol,
                     const float* __restrict__ sval, const float* __restrict__ H,
                     const float* __restrict__ G1, float* __restrict__ out) {
    constexpr int W = 64;
    int i = blockIdx.x * 4 + (threadIdx.x >> 6);
    if (i >= 2 * B) return;
    int r = (i < B) ? userIdx[i] : itemIdx[i - B] + USER_NUM;
    int base = threadIdx.x & 63;
    float acc = G1[(size_t)r * W + base];
    int e0 = row_ptr[r], e1 = row_ptr[r + 1];
    int e = e0;
    for (; e + 1 < e1; e += 2) {
        int c0 = scol[e], c1 = scol[e + 1];
        float v0 = sval[e], v1 = sval[e + 1];
        acc += v0 * H[(size_t)c0 * W + base] + v1 * H[(size_t)c1 * W + base];
    }
    if (e < e1)
        acc += sval[e] * H[(size_t)scol[e] * W + base];
    out[(size_t)r * W + base] = acc;
}

// ---------------------------------------------------------------------------

extern "C" void kernel_launch(void* const* d_in, const int* in_sizes, int n_in,
                              void* d_out, int out_size, void* d_ws, size_t ws_size,
                              hipStream_t stream) {
    const int* userIdx  = (const int*)d_in[0];
    const int* itemIdx  = (const int*)d_in[1];
    const int* edge_row = (const int*)d_in[2];
    const int* edge_col = (const int*)d_in[3];
    const float* edge_val = (const float*)d_in[4];
    const float* uEmbd  = (const float*)d_in[5];
    const float* iEmbd  = (const float*)d_in[6];
    const float* W1_0 = (const float*)d_in[7];
    const float* b1_0 = (const float*)d_in[8];
    const float* W2_0 = (const float*)d_in[9];
    const float* b2_0 = (const float*)d_in[10];
    const float* W1_1 = (const float*)d_in[11];
    const float* b1_1 = (const float*)d_in[12];
    const float* W2_1 = (const float*)d_in[13];
    const float* b2_1 = (const float*)d_in[14];
    const float* T1_W = (const float*)d_in[15];
    const float* T1_b = (const float*)d_in[16];
    const float* T2_W = (const float*)d_in[17];
    const float* T2_b = (const float*)d_in[18];
    const float* T3_W = (const float*)d_in[19];
    const float* T3_b = (const float*)d_in[20];
    float* out = (float*)d_out;

    const int B   = in_sizes[0];
    const int NNZ = in_sizes[2];
    const int N   = NTOT;

    // ---- workspace carve-up (bytes, 256-aligned) ----
    uint8_t* ws = (uint8_t*)d_ws;
    size_t off = 0;
    auto alloc = [&](size_t bytes) {
        void* p = ws + off;
        off += (bytes + 255) & ~(size_t)255;
        return p;
    };
    float* bufA = (float*)alloc((size_t)N * 128 * 4);  // G1_0; later G1_1 | H_1
    float* bufB = (float*)alloc((size_t)N * 128 * 4);  // H_0;  later f2
    float* f1   = (float*)alloc((size_t)N * 128 * 4);
    int*   counts  = (int*)alloc((size_t)2 * N * 4);   // counts[N] + fill[N]
    int*   fill    = counts + N;
    int*   row_ptr = (int*)alloc((size_t)(N + 1) * 4);
    int*   blk_sums= (int*)alloc(128 * 4);
    int*   bar     = (int*)alloc(256);                 // grid-barrier counter
    int*   scol    = (int*)alloc((size_t)NNZ * 4);
    float* sval    = (float*)alloc((size_t)NNZ * 4);
    // pre-split weight matrices (hi/lo bf16 stored as ushort)
    ushort* W10h = (ushort*)alloc(128 * 256 * 2);
    ushort* W10l = (ushort*)alloc(128 * 256 * 2);
    ushort* W20h = (ushort*)alloc(128 * 256 * 2);
    ushort* W20l = (ushort*)alloc(128 * 256 * 2);
    ushort* W11h = (ushort*)alloc(64 * 128 * 2);
    ushort* W11l = (ushort*)alloc(64 * 128 * 2);
    ushort* W21h = (ushort*)alloc(64 * 128 * 2);
    ushort* W21l = (ushort*)alloc(64 * 128 * 2);
    ushort* T1h  = (ushort*)alloc(64 * 896 * 2);
    ushort* T1l  = (ushort*)alloc(64 * 896 * 2);
    (void)ws_size; (void)n_in; (void)out_size;

    float* G1_0 = bufA;
    float* H_0  = bufB;
    float* G1_1 = bufA;
    float* H_1  = bufA + (size_t)N * 64;
    float* f2   = bufB;

    // ---- init (zero counts+fill+bar) + split weights: one launch, no deps ----
    {
        const int n2 = 2 * N;                         // 200000 >= 139264
        init_and_split<<<(n2 + 255) / 256, 256, 0, stream>>>(
            counts, n2, bar, W1_0, W2_0, W1_1, W2_1, T1_W,
            W10h, W10l, W20h, W20l, W11h, W11l, W21h, W21l, T1h, T1l);
    }

    // ---- build CSR: ONE kernel, software grid barrier (98 co-resident blocks) ----
    {
        int nb = (N + 1023) / 1024;   // 98
        build_csr_spin<<<nb, 1024, 0, stream>>>(edge_row, edge_col, edge_val,
                                                counts, row_ptr, blk_sums,
                                                scol, sval, N, NNZ, bar);
    }

    // ---- layer 0: G1_0 = F@W1_0^T (+biases), H_0 = F@W1_0^T + (F*F)@W2_0^T ----
    {
        dim3 grid(2, (N + 127) / 128);   // TN=64, Nout=128
        gemm_dual_mfma<64, 256><<<grid, 256, 0, stream>>>(
            uEmbd, iEmbd, USER_NUM, W10h, W10l, W20h, W20l, b1_0, b2_0, G1_0, H_0, N, 128);
    }
    // f1 = spmm(H_0) + G1_0   (biases already in G1_0) — all rows (L1 needs them)
    spmm_fused<2><<<(N + 3) / 4, 256, 0, stream>>>(row_ptr, scol, sval, H_0, G1_0, f1, N);

    // ---- layer 1: G1_1 = f1@W1_1^T (+biases), H_1 = f1@W1_1^T + (f1*f1)@W2_1^T ----
    {
        dim3 grid(1, (N + 127) / 128);   // TN=64, Nout=64
        gemm_dual_mfma<64, 128><<<grid, 256, 0, stream>>>(
            f1, f1, N, W11h, W11l, W21h, W21l, b1_1, b2_1, G1_1, H_1, N, 64);
    }
    // f2 = spmm(H_1) + G1_1 — ONLY at gathered rows (f2 feeds just the t1 gather)
    spmm_fused_list<<<(2 * B + 3) / 4, 256, 0, stream>>>(
        userIdx, itemIdx, B, row_ptr, scol, sval, H_1, G1_1, f2);

    // ---- fused gather + T1 GEMM + T2/T3 tail (writes out directly) ----
    {
        dim3 grid(1, (B + 63) / 64);     // TM=64 -> 256 blocks: full GPU
        gemm_t1_mfma<64, 896><<<grid, 256, 0, stream>>>(
            userIdx, itemIdx, uEmbd, iEmbd, f1, f2, T1h, T1l, T1_b,
            T2_W, T2_b, T3_W, T3_b, out, B);
    }
}

// Round 14
// 394.163 us; speedup vs baseline: 1.0615x; 1.0615x over previous
//
#include <hip/hip_runtime.h>
#include <hip/hip_bf16.h>
#include <cstdint>

#define USER_NUM 30000
#define ITEM_NUM 70000
#define NTOT     100000   // USER_NUM + ITEM_NUM

typedef __attribute__((ext_vector_type(8))) short bf16x8;
typedef __attribute__((ext_vector_type(8))) ushort u16x8;
typedef __attribute__((ext_vector_type(4))) float f32x4;
typedef __attribute__((ext_vector_type(4))) unsigned int u32x4;

// async global->LDS DMA, 16B per lane (dest = wave-uniform base + lane*16)
typedef __attribute__((address_space(1))) const unsigned int gu32;
typedef __attribute__((address_space(3))) unsigned int lu32;
__device__ __forceinline__ void dma16(const void* g, void* l) {
    __builtin_amdgcn_global_load_lds((gu32*)g, (lu32*)l, 16, 0, 0);
}

// fp32 -> (hi, lo) bf16 pair via truncation; a ~= hi + lo to ~2^-16 rel.
__device__ __forceinline__ void split2(float x, ushort& h, ushort& l) {
    unsigned u = __builtin_bit_cast(unsigned int, x);
    h = (ushort)(u >> 16);
    float hf = __builtin_bit_cast(float, u & 0xffff0000u);
    float lo = x - hf;
    l = (ushort)(__builtin_bit_cast(unsigned int, lo) >> 16);
}

// pack hi16(x0) into low half, hi16(x1) into high half (one v_perm_b32)
__device__ __forceinline__ unsigned int pk_hi(unsigned int x0, unsigned int x1) {
    return __builtin_amdgcn_perm(x1, x0, 0x07060302u);
}

// convert 8 fp32 -> bf16 hi/lo of value and of square (v_perm-packed pairs)
__device__ __forceinline__ void cvt8(const float4& a, const float4& b,
                                     bf16x8& vh, bf16x8& vl, bf16x8& sh, bf16x8& sl) {
    const float f[8] = {a.x, a.y, a.z, a.w, b.x, b.y, b.z, b.w};
    unsigned int ph[4], pl[4], qh[4], ql[4];
#pragma unroll
    for (int p = 0; p < 4; ++p) {
        float f0 = f[2 * p], f1 = f[2 * p + 1];
        unsigned int u0 = __builtin_bit_cast(unsigned int, f0);
        unsigned int u1 = __builtin_bit_cast(unsigned int, f1);
        ph[p] = pk_hi(u0, u1);
        float hf0 = __builtin_bit_cast(float, u0 & 0xffff0000u);
        float hf1 = __builtin_bit_cast(float, u1 & 0xffff0000u);
        pl[p] = pk_hi(__builtin_bit_cast(unsigned int, f0 - hf0),
                      __builtin_bit_cast(unsigned int, f1 - hf1));
        float s0 = f0 * f0, s1 = f1 * f1;
        unsigned int v0 = __builtin_bit_cast(unsigned int, s0);
        unsigned int v1 = __builtin_bit_cast(unsigned int, s1);
        qh[p] = pk_hi(v0, v1);
        float sh0 = __builtin_bit_cast(float, v0 & 0xffff0000u);
        float sh1 = __builtin_bit_cast(float, v1 & 0xffff0000u);
        ql[p] = pk_hi(__builtin_bit_cast(unsigned int, s0 - sh0),
                      __builtin_bit_cast(unsigned int, s1 - sh1));
    }
    vh = __builtin_bit_cast(bf16x8, u32x4{ph[0], ph[1], ph[2], ph[3]});
    vl = __builtin_bit_cast(bf16x8, u32x4{pl[0], pl[1], pl[2], pl[3]});
    sh = __builtin_bit_cast(bf16x8, u32x4{qh[0], qh[1], qh[2], qh[3]});
    sl = __builtin_bit_cast(bf16x8, u32x4{ql[0], ql[1], ql[2], ql[3]});
}

// ---------------------------------------------------------------------------
// CSR build kernels. LESSONS: v12 cooperative-launch fusion crashed under
// graph capture; v15 software-spin-barrier fusion cost +22us (cross-XCD
// polling + slowest-block serialization > 3 launch gaps). Plain serial
// kernels are the measured optimum for this chain.
// ---------------------------------------------------------------------------

// zero counts+fill AND split all 5 weight matrices (independent work, 1 launch)
__global__ void init_and_split(int* __restrict__ counts, int n2,
                               const float* __restrict__ W10, const float* __restrict__ W20,
                               const float* __restrict__ W11, const float* __restrict__ W21,
                               const float* __restrict__ T1,
                               ushort* __restrict__ W10h, ushort* __restrict__ W10l,
                               ushort* __restrict__ W20h, ushort* __restrict__ W20l,
                               ushort* __restrict__ W11h, ushort* __restrict__ W11l,
                               ushort* __restrict__ W21h, ushort* __restrict__ W21l,
                               ushort* __restrict__ T1h,  ushort* __restrict__ T1l) {
    int i = blockIdx.x * blockDim.x + threadIdx.x;
    if (i < n2) counts[i] = 0;
    int j = i;
    if (j < 139264) {
        const float* src; ushort *dh, *dl;
        if (j < 32768)                   { src = W10; dh = W10h; dl = W10l; }
        else if ((j -= 32768) < 32768)   { src = W20; dh = W20h; dl = W20l; }
        else if ((j -= 32768) < 8192)    { src = W11; dh = W11h; dl = W11l; }
        else if ((j -= 8192) < 8192)     { src = W21; dh = W21h; dl = W21l; }
        else                             { j -= 8192; src = T1; dh = T1h; dl = T1l; }
        ushort h, l;
        split2(src[j], h, l);
        dh[j] = h;
        dl[j] = l;
    }
}

__global__ void hist_rows(const int* __restrict__ erow, int* __restrict__ counts, int nnz) {
    int i = blockIdx.x * blockDim.x + threadIdx.x;
    if (i < nnz) atomicAdd(&counts[erow[i]], 1);
}

__global__ void scan_block(const int* __restrict__ counts, int* __restrict__ row_ptr,
                           int* __restrict__ blk_sums, int n) {
    __shared__ int sd[1024];
    int i = blockIdx.x * 1024 + threadIdx.x;
    int v = (i < n) ? counts[i] : 0;
    sd[threadIdx.x] = v;
    __syncthreads();
    for (int off = 1; off < 1024; off <<= 1) {
        int t = (threadIdx.x >= off) ? sd[threadIdx.x - off] : 0;
        __syncthreads();
        sd[threadIdx.x] += t;
        __syncthreads();
    }
    if (i < n) row_ptr[i] = sd[threadIdx.x] - v;   // block-local exclusive
    if (threadIdx.x == 1023) blk_sums[blockIdx.x] = sd[1023];
}

// Each block redundantly inclusive-scans the (<=128) block sums in LDS, then
// adds exclusive_prefix[blockIdx.x] = sd[blockIdx.x-1] to its row_ptr slice.
__global__ void scan_add2(int* __restrict__ row_ptr, const int* __restrict__ blk_sums,
                          int n, int nnz, int nb) {
    __shared__ int sd[128];
    if (threadIdx.x < 128)
        sd[threadIdx.x] = ((int)threadIdx.x < nb) ? blk_sums[threadIdx.x] : 0;
    __syncthreads();
    for (int off = 1; off < 128; off <<= 1) {
        int t = (threadIdx.x < 128 && threadIdx.x >= (unsigned)off) ? sd[threadIdx.x - off] : 0;
        __syncthreads();
        if (threadIdx.x < 128) sd[threadIdx.x] += t;
        __syncthreads();
    }
    int add = (blockIdx.x == 0) ? 0 : sd[blockIdx.x - 1];
    int i = blockIdx.x * 1024 + threadIdx.x;
    if (i < n) row_ptr[i] += add;
    if (blockIdx.x == 0 && threadIdx.x == 0) row_ptr[n] = nnz;
}

__global__ void scatter_edges(const int* __restrict__ erow, const int* __restrict__ ecol,
                              const float* __restrict__ eval,
                              const int* __restrict__ row_ptr, int* __restrict__ fill,
                              int* __restrict__ scol, float* __restrict__ sval, int nnz) {
    int i = blockIdx.x * blockDim.x + threadIdx.x;
    if (i >= nnz) return;
    int r = erow[i];
    int pos = row_ptr[r] + atomicAdd(&fill[r], 1);
    scol[pos] = ecol[i];
    sval[pos] = eval[i];
}

// ---------------------------------------------------------------------------
// Dual split-bf16 MFMA GEMM, v8 structure (DMA staging + LDS double-buffer):
//   C1 = A @ W1^T + b1 + b2 ;  C2 = (A @ W1^T) + (A*A) @ W2^T
// TM=128, block 256 = 4 waves, wave tile 32 rows x TN (row-exclusive). BK=32.
// PLATEAU (v7-v10): all staging structures land 91-102us; no pipe >28% busy.
// Frozen.
// ---------------------------------------------------------------------------

template <int TN, int KK>
__global__ __launch_bounds__(256, 2)
void gemm_dual_mfma(const float* __restrict__ xa, const float* __restrict__ xb, int split,
                    const ushort* __restrict__ W1h, const ushort* __restrict__ W1l,
                    const ushort* __restrict__ W2h, const ushort* __restrict__ W2l,
                    const float* __restrict__ bias1, const float* __restrict__ bias2,
                    float* __restrict__ C1, float* __restrict__ C2,
                    int M, int Nout) {
    constexpr int TM = 128, BK = 32;
    constexpr int NITER = KK / BK;
    constexpr int NI = TN / 16;             // 4
    constexpr int MI = 2;                   // 32 rows per wave
    static_assert(NITER % 2 == 0, "double-buffer unroll needs even NITER");
    __shared__ float Araw0[TM * BK], Araw1[TM * BK];      // 2 x 16KB, linear [128][32]
    __shared__ ushort Wt0[4][TN * BK], Wt1[4][TN * BK];   // 2 x 16KB, linear [64][32]

    const int m0 = blockIdx.y * TM;
    const int n0 = blockIdx.x * TN;
    const int t  = threadIdx.x;
    const int lane = t & 63, w = t >> 6;
    const int lm = lane & 15, lq = lane >> 4;

    // ---- A staging map: 4 DMA calls/wave ----
    const float* asrc[4];
#pragma unroll
    for (int c = 0; c < 4; ++c) {
        int loff = w * 4096 + c * 1024 + lane * 16;   // byte offset in A buffer
        int row  = loff >> 7;                          // 128 B rows
        int slot = (loff >> 4) & 7;
        int gm = m0 + row;
        const float* rp = xa;
        if (gm < M) rp = (gm < split) ? xa + (size_t)gm * KK
                                      : xb + (size_t)(gm - split) * KK;
        asrc[c] = rp + (slot ^ (row & 7)) * 4;         // pre-swizzled source
    }
    // ---- W staging map: 1 DMA call/wave/array ----
    const ushort* wsrc[4] = {W1h, W1l, W2h, W2l};
    const ushort* wptr[4];
#pragma unroll
    for (int p = 0; p < 4; ++p) {
        int loff = w * 1024 + lane * 16;               // byte offset in array
        int row  = loff >> 6;                          // 64 B rows
        int slot = (loff >> 4) & 3;
        wptr[p] = wsrc[p] + (size_t)(n0 + row) * KK + (slot ^ (row & 3)) * 8;
    }

    // read-side swizzled offsets (elements); row&7 == lm&7, row&3 == lm&3
    const int sA0 = ((lq * 2 + 0) ^ (lm & 7)) * 4;
    const int sA1 = ((lq * 2 + 1) ^ (lm & 7)) * 4;
    const int sW  = (lq ^ (lm & 3)) * 8;

    f32x4 acc1[MI][NI] = {};
    f32x4 acc2[MI][NI] = {};

    auto stage = [&](float* Ad, ushort (*Wd)[TN * BK], int k0) {
#pragma unroll
        for (int c = 0; c < 4; ++c)
            dma16(asrc[c] + k0, (char*)Ad + w * 4096 + c * 1024);
#pragma unroll
        for (int p = 0; p < 4; ++p)
            dma16(wptr[p] + k0, (char*)Wd + p * 4096 + w * 1024);
    };

    auto compute = [&](const float* Ar, const ushort (*Wr)[TN * BK]) {
#pragma unroll
        for (int mi = 0; mi < MI; ++mi) {
            const int row = w * 32 + mi * 16 + lm;
            const float* ap = Ar + row * 32;
            float4 x0 = *(const float4*)(ap + sA0);
            float4 x1 = *(const float4*)(ap + sA1);
            bf16x8 vah, val, vqh, vql;
            cvt8(x0, x1, vah, val, vqh, vql);
#pragma unroll
            for (int ni = 0; ni < NI; ++ni) {
                const int woff = (ni * 16 + lm) * 32 + sW;
                bf16x8 b1h = *(const bf16x8*)(Wr[0] + woff);
                bf16x8 b1l = *(const bf16x8*)(Wr[1] + woff);
                bf16x8 b2h = *(const bf16x8*)(Wr[2] + woff);
                bf16x8 b2l = *(const bf16x8*)(Wr[3] + woff);
                acc1[mi][ni] = __builtin_amdgcn_mfma_f32_16x16x32_bf16(vah, b1h, acc1[mi][ni], 0, 0, 0);
                acc1[mi][ni] = __builtin_amdgcn_mfma_f32_16x16x32_bf16(vah, b1l, acc1[mi][ni], 0, 0, 0);
                acc1[mi][ni] = __builtin_amdgcn_mfma_f32_16x16x32_bf16(val, b1h, acc1[mi][ni], 0, 0, 0);
                acc2[mi][ni] = __builtin_amdgcn_mfma_f32_16x16x32_bf16(vqh, b2h, acc2[mi][ni], 0, 0, 0);
                acc2[mi][ni] = __builtin_amdgcn_mfma_f32_16x16x32_bf16(vqh, b2l, acc2[mi][ni], 0, 0, 0);
                acc2[mi][ni] = __builtin_amdgcn_mfma_f32_16x16x32_bf16(vql, b2h, acc2[mi][ni], 0, 0, 0);
            }
        }
    };

    // prologue: tile 0 latency exposed once
    stage(Araw0, Wt0, 0);
    __syncthreads();

    for (int it = 0; it < NITER; it += 2) {
        stage(Araw1, Wt1, (it + 1) * BK);     // in flight during compute
        compute(Araw0, Wt0);
        __syncthreads();
        if (it + 2 < NITER) stage(Araw0, Wt0, (it + 2) * BK);
        compute(Araw1, Wt1);
        __syncthreads();
    }

    // ---- epilogue: C/D layout col=lane&15, row=lq*4+r; biases folded into C1 ----
#pragma unroll
    for (int mi = 0; mi < MI; ++mi)
#pragma unroll
        for (int ni = 0; ni < NI; ++ni)
#pragma unroll
            for (int r = 0; r < 4; ++r) {
                int gm = m0 + w * 32 + mi * 16 + lq * 4 + r;
                int gn = n0 + ni * 16 + lm;
                if (gm < M && gn < Nout) {
                    size_t o = (size_t)gm * Nout + gn;
                    float g1 = acc1[mi][ni][r];
                    C1[o] = g1 + bias1[gn] + bias2[gn];
                    C2[o] = g1 + acc2[mi][ni][r];
                }
            }
}

// ---------------------------------------------------------------------------
// T1 GEMM with fused gather + FUSED T2/T3 TAIL (v11, kept):
//   e1 = relu( [final[u] ; final[it+U]] @ T1_W^T + T1_b )   (64 cols, in LDS)
//   out[b] = T3_W . relu(T2_W @ e1[b] + T2_b) + T3_b
// TM=64, grid (1,256): full GPU. e1 never touches global.
// ---------------------------------------------------------------------------

template <int TN, int KK>
__global__ __launch_bounds__(256, 4)
void gemm_t1_mfma(const int* __restrict__ userIdx, const int* __restrict__ itemIdx,
                  const float* __restrict__ uEmbd, const float* __restrict__ iEmbd,
                  const float* __restrict__ f1, const float* __restrict__ f2,
                  const ushort* __restrict__ Wh, const ushort* __restrict__ Wl,
                  const float* __restrict__ bias,
                  const float* __restrict__ T2_W, const float* __restrict__ T2_b,
                  const float* __restrict__ T3_W, const float* __restrict__ T3_b,
                  float* __restrict__ out, int M) {
    constexpr int TM = 64, BK = 32, SR = 40;
    constexpr int NITER = KK / BK;            // 28
    constexpr int WTM = 32, WTN = TN / 2;     // 32 x 32 wave tiles
    constexpr int MI = WTM / 16, NI = WTN / 16;
    __shared__ ushort Ah[TM * SR], Al[TM * SR];   // 2 x 5120 B
    __shared__ float e1t[64][68];                 // 17408 B; total 27.6KB -> 4 blk/CU

    const int m0 = blockIdx.y * TM;
    const int n0 = blockIdx.x * TN;               // always 0 (grid.x = 1)
    const int t  = threadIdx.x;
    const int lane = t & 63, w = t >> 6;
    const int wm = w & 1, wn = w >> 1;
    const int lm = lane & 15, lq = lane >> 4;

    const int srow = t >> 2, spart = t & 3;   // 4 threads per row, 8 floats each
    const int b = m0 + srow;
    const bool svalid = (b < M);
    int unode = 0, gnode = 0;
    if (svalid) { unode = userIdx[b]; gnode = itemIdx[b] + USER_NUM; }
    const int sbase = srow * SR + spart * 8;

    auto gload = [&](int it, float4* v) {
        v[0] = float4{0.f, 0.f, 0.f, 0.f};
        v[1] = float4{0.f, 0.f, 0.f, 0.f};
        if (!svalid) return;
        int c0 = it * BK + spart * 8;
        int node = (c0 < 448) ? unode : gnode;
        int cc = (c0 < 448) ? c0 : c0 - 448;
        const float* p;
        if (cc < 256)
            p = (node < USER_NUM) ? uEmbd + (size_t)node * 256 + cc
                                  : iEmbd + (size_t)(node - USER_NUM) * 256 + cc;
        else if (cc < 384) p = f1 + (size_t)node * 128 + (cc - 256);
        else               p = f2 + (size_t)node * 64  + (cc - 384);
        v[0] = *(const float4*)p;
        v[1] = *(const float4*)(p + 4);
    };

    f32x4 acc[MI][NI] = {};

    float4 cur[2];
    gload(0, cur);

    for (int it = 0; it < NITER; ++it) {
        // ---- write current tile (hi/lo split) to LDS ----
        {
            ushort hb[8], lb[8];
            const float av[8] = {cur[0].x, cur[0].y, cur[0].z, cur[0].w,
                                 cur[1].x, cur[1].y, cur[1].z, cur[1].w};
#pragma unroll
            for (int j = 0; j < 8; ++j) split2(av[j], hb[j], lb[j]);
            *(u16x8*)(Ah + sbase) = *(const u16x8*)&hb[0];
            *(u16x8*)(Al + sbase) = *(const u16x8*)&lb[0];
        }
        __syncthreads();

        // ---- T14 issue-early: next tile's gather loads fly during compute ----
        float4 nxt[2];
        if (it + 1 < NITER) gload(it + 1, nxt);

        const int k0 = it * BK;
        bf16x8 bh[NI], bl[NI];
#pragma unroll
        for (int ni = 0; ni < NI; ++ni) {
            size_t wo = (size_t)(n0 + wn * WTN + ni * 16 + lm) * KK + k0 + lq * 8;
            bh[ni] = *(const bf16x8*)(Wh + wo);
            bl[ni] = *(const bf16x8*)(Wl + wo);
        }
#pragma unroll
        for (int mi = 0; mi < MI; ++mi) {
            int off = (wm * WTM + mi * 16 + lm) * SR + lq * 8;
            bf16x8 ah = *(const bf16x8*)(Ah + off);
            bf16x8 al = *(const bf16x8*)(Al + off);
#pragma unroll
            for (int ni = 0; ni < NI; ++ni) {
                acc[mi][ni] = __builtin_amdgcn_mfma_f32_16x16x32_bf16(ah, bh[ni], acc[mi][ni], 0, 0, 0);
                acc[mi][ni] = __builtin_amdgcn_mfma_f32_16x16x32_bf16(ah, bl[ni], acc[mi][ni], 0, 0, 0);
                acc[mi][ni] = __builtin_amdgcn_mfma_f32_16x16x32_bf16(al, bh[ni], acc[mi][ni], 0, 0, 0);
            }
        }
        __syncthreads();
        cur[0] = nxt[0];
        cur[1] = nxt[1];
    }

    // ---- e1 tile -> LDS (relu + bias), then fused T2+T3 tail ----
#pragma unroll
    for (int mi = 0; mi < MI; ++mi)
#pragma unroll
        for (int ni = 0; ni < NI; ++ni)
#pragma unroll
            for (int r = 0; r < 4; ++r) {
                int lr = wm * WTM + mi * 16 + lq * 4 + r;   // 0..63
                int lc = wn * WTN + ni * 16 + lm;           // 0..63
                e1t[lr][lc] = fmaxf(acc[mi][ni][r] + bias[lc], 0.f);
            }
    __syncthreads();

    {
        const int row = t >> 2;          // 0..63: local e1 row
        const int gb  = m0 + row;
        float s = 0.f;
        if (gb < M) {
#pragma unroll
            for (int jj = 0; jj < 8; ++jj) {
                int j = (t & 3) * 8 + jj;            // 0..31: T2 row
                const float* wr = T2_W + j * 64;
                float d = T2_b[j];
#pragma unroll
                for (int k = 0; k < 64; ++k) d += e1t[row][k] * wr[k];
                s += fmaxf(d, 0.f) * T3_W[j];
            }
        }
        s += __shfl_down(s, 2, 4);
        s += __shfl_down(s, 1, 4);
        if ((t & 3) == 0 && gb < M) out[gb] = s + T3_b[0];
    }
}

// ---------------------------------------------------------------------------
// Fused SPMM epilogue (biases pre-folded into G1):
//   out[r,:] = sum_e val_e * H[col_e,:] + G1[r,:]
// Layer 0 uses the dense-row form (all N rows needed by the L1 GEMM).
// ---------------------------------------------------------------------------

template <int VEC>
__global__ __launch_bounds__(256)
void spmm_fused(const int* __restrict__ row_ptr, const int* __restrict__ scol,
                const float* __restrict__ sval, const float* __restrict__ H,
                const float* __restrict__ G1, float* __restrict__ out, int n) {
    constexpr int W = 64 * VEC;
    int r = blockIdx.x * 4 + (threadIdx.x >> 6);
    if (r >= n) return;
    int base = (threadIdx.x & 63) * VEC;
    float acc[VEC];
    const float* g = G1 + (size_t)r * W + base;
#pragma unroll
    for (int v = 0; v < VEC; ++v) acc[v] = g[v];
    int e0 = row_ptr[r], e1 = row_ptr[r + 1];
    int e = e0;
    for (; e + 1 < e1; e += 2) {
        int c0 = scol[e], c1 = scol[e + 1];
        float v0 = sval[e], v1 = sval[e + 1];
        const float* h0 = H + (size_t)c0 * W + base;
        const float* h1 = H + (size_t)c1 * W + base;
#pragma unroll
        for (int v = 0; v < VEC; ++v) acc[v] += v0 * h0[v] + v1 * h1[v];
    }
    if (e < e1) {
        int c = scol[e];
        float val = sval[e];
        const float* h = H + (size_t)c * W + base;
#pragma unroll
        for (int v = 0; v < VEC; ++v) acc[v] += val * h[v];
    }
    float* o = out + (size_t)r * W + base;
#pragma unroll
    for (int v = 0; v < VEC; ++v) o[v] = acc[v];
}

// ---------------------------------------------------------------------------
// List-driven SPMM for layer 1 (v14): f2 is consumed ONLY by the t1 gather at
// rows {userIdx} ∪ {itemIdx+USER_NUM}; compute just those 2B row-instances
// (~3x less work than all N rows). Duplicates write identical values.
// ---------------------------------------------------------------------------

__global__ __launch_bounds__(256)
void spmm_fused_list(const int* __restrict__ userIdx, const int* __restrict__ itemIdx,
                     int B,
                     const int* __restrict__ row_ptr, const int* __restrict__ scol,
                     const float* __restrict__ sval, const float* __restrict__ H,
                     const float* __restrict__ G1, float* __restrict__ out) {
    constexpr int W = 64;
    int i = blockIdx.x * 4 + (threadIdx.x >> 6);
    if (i >= 2 * B) return;
    int r = (i < B) ? userIdx[i] : itemIdx[i - B] + USER_NUM;
    int base = threadIdx.x & 63;
    float acc = G1[(size_t)r * W + base];
    int e0 = row_ptr[r], e1 = row_ptr[r + 1];
    int e = e0;
    for (; e + 1 < e1; e += 2) {
        int c0 = scol[e], c1 = scol[e + 1];
        float v0 = sval[e], v1 = sval[e + 1];
        acc += v0 * H[(size_t)c0 * W + base] + v1 * H[(size_t)c1 * W + base];
    }
    if (e < e1)
        acc += sval[e] * H[(size_t)scol[e] * W + base];
    out[(size_t)r * W + base] = acc;
}

// ---------------------------------------------------------------------------

extern "C" void kernel_launch(void* const* d_in, const int* in_sizes, int n_in,
                              void* d_out, int out_size, void* d_ws, size_t ws_size,
                              hipStream_t stream) {
    const int* userIdx  = (const int*)d_in[0];
    const int* itemIdx  = (const int*)d_in[1];
    const int* edge_row = (const int*)d_in[2];
    const int* edge_col = (const int*)d_in[3];
    const float* edge_val = (const float*)d_in[4];
    const float* uEmbd  = (const float*)d_in[5];
    const float* iEmbd  = (const float*)d_in[6];
    const float* W1_0 = (const float*)d_in[7];
    const float* b1_0 = (const float*)d_in[8];
    const float* W2_0 = (const float*)d_in[9];
    const float* b2_0 = (const float*)d_in[10];
    const float* W1_1 = (const float*)d_in[11];
    const float* b1_1 = (const float*)d_in[12];
    const float* W2_1 = (const float*)d_in[13];
    const float* b2_1 = (const float*)d_in[14];
    const float* T1_W = (const float*)d_in[15];
    const float* T1_b = (const float*)d_in[16];
    const float* T2_W = (const float*)d_in[17];
    const float* T2_b = (const float*)d_in[18];
    const float* T3_W = (const float*)d_in[19];
    const float* T3_b = (const float*)d_in[20];
    float* out = (float*)d_out;

    const int B   = in_sizes[0];
    const int NNZ = in_sizes[2];
    const int N   = NTOT;

    // ---- workspace carve-up (bytes, 256-aligned) ----
    uint8_t* ws = (uint8_t*)d_ws;
    size_t off = 0;
    auto alloc = [&](size_t bytes) {
        void* p = ws + off;
        off += (bytes + 255) & ~(size_t)255;
        return p;
    };
    float* bufA = (float*)alloc((size_t)N * 128 * 4);  // G1_0; later G1_1 | H_1
    float* bufB = (float*)alloc((size_t)N * 128 * 4);  // H_0;  later f2
    float* f1   = (float*)alloc((size_t)N * 128 * 4);
    int*   counts  = (int*)alloc((size_t)2 * N * 4);   // counts[N] + fill[N]
    int*   fill    = counts + N;
    int*   row_ptr = (int*)alloc((size_t)(N + 1) * 4);
    int*   blk_sums= (int*)alloc(128 * 4);
    int*   scol    = (int*)alloc((size_t)NNZ * 4);
    float* sval    = (float*)alloc((size_t)NNZ * 4);
    // pre-split weight matrices (hi/lo bf16 stored as ushort)
    ushort* W10h = (ushort*)alloc(128 * 256 * 2);
    ushort* W10l = (ushort*)alloc(128 * 256 * 2);
    ushort* W20h = (ushort*)alloc(128 * 256 * 2);
    ushort* W20l = (ushort*)alloc(128 * 256 * 2);
    ushort* W11h = (ushort*)alloc(64 * 128 * 2);
    ushort* W11l = (ushort*)alloc(64 * 128 * 2);
    ushort* W21h = (ushort*)alloc(64 * 128 * 2);
    ushort* W21l = (ushort*)alloc(64 * 128 * 2);
    ushort* T1h  = (ushort*)alloc(64 * 896 * 2);
    ushort* T1l  = (ushort*)alloc(64 * 896 * 2);
    (void)ws_size; (void)n_in; (void)out_size;

    float* G1_0 = bufA;
    float* H_0  = bufB;
    float* G1_1 = bufA;
    float* H_1  = bufA + (size_t)N * 64;
    float* f2   = bufB;

    // ---- init (zero counts+fill) + split weights: one launch, no deps ----
    {
        const int n2 = 2 * N;                         // 200000 >= 139264
        init_and_split<<<(n2 + 255) / 256, 256, 0, stream>>>(
            counts, n2, W1_0, W2_0, W1_1, W2_1, T1_W,
            W10h, W10l, W20h, W20l, W11h, W11l, W21h, W21l, T1h, T1l);
    }

    // ---- build CSR (4 launches, stream-ordered deps) ----
    hist_rows<<<(NNZ + 255) / 256, 256, 0, stream>>>(edge_row, counts, NNZ);
    int nb = (N + 1023) / 1024;   // 98
    scan_block<<<nb, 1024, 0, stream>>>(counts, row_ptr, blk_sums, N);
    scan_add2<<<nb, 1024, 0, stream>>>(row_ptr, blk_sums, N, NNZ, nb);
    scatter_edges<<<(NNZ + 255) / 256, 256, 0, stream>>>(edge_row, edge_col, edge_val,
                                                         row_ptr, fill, scol, sval, NNZ);

    // ---- layer 0: G1_0 = F@W1_0^T (+biases), H_0 = F@W1_0^T + (F*F)@W2_0^T ----
    {
        dim3 grid(2, (N + 127) / 128);   // TN=64, Nout=128
        gemm_dual_mfma<64, 256><<<grid, 256, 0, stream>>>(
            uEmbd, iEmbd, USER_NUM, W10h, W10l, W20h, W20l, b1_0, b2_0, G1_0, H_0, N, 128);
    }
    // f1 = spmm(H_0) + G1_0   (biases already in G1_0) — all rows (L1 needs them)
    spmm_fused<2><<<(N + 3) / 4, 256, 0, stream>>>(row_ptr, scol, sval, H_0, G1_0, f1, N);

    // ---- layer 1: G1_1 = f1@W1_1^T (+biases), H_1 = f1@W1_1^T + (f1*f1)@W2_1^T ----
    {
        dim3 grid(1, (N + 127) / 128);   // TN=64, Nout=64
        gemm_dual_mfma<64, 128><<<grid, 256, 0, stream>>>(
            f1, f1, N, W11h, W11l, W21h, W21l, b1_1, b2_1, G1_1, H_1, N, 64);
    }
    // f2 = spmm(H_1) + G1_1 — ONLY at gathered rows (f2 feeds just the t1 gather)
    spmm_fused_list<<<(2 * B + 3) / 4, 256, 0, stream>>>(
        userIdx, itemIdx, B, row_ptr, scol, sval, H_1, G1_1, f2);

    // ---- fused gather + T1 GEMM + T2/T3 tail (writes out directly) ----
    {
        dim3 grid(1, (B + 63) / 64);     // TM=64 -> 256 blocks: full GPU
        gemm_t1_mfma<64, 896><<<grid, 256, 0, stream>>>(
            userIdx, itemIdx, uEmbd, iEmbd, f1, f2, T1h, T1l, T1_b,
            T2_W, T2_b, T3_W, T3_b, out, B);
    }
}